// Round 1
// baseline (732.467 us; speedup 1.0000x reference)
//
#include <hip/hip_runtime.h>
#include <hip/hip_bf16.h>
#include <math.h>

// Problem constants
#define BB 32
#define TT 2048
#define EE 1024
#define DD 1024
#define MM (BB * TT)   // 65536 rows
#define CC 10
#define FW 201

typedef __attribute__((ext_vector_type(8))) short short8;
typedef __attribute__((ext_vector_type(4))) float f32x4;
typedef __attribute__((ext_vector_type(4))) float f4;
typedef __attribute__((ext_vector_type(8))) unsigned short u16x8;
typedef unsigned short u16;

__device__ __forceinline__ u16 f2bf(float f) {
  __hip_bfloat16 h = __float2bfloat16(f);
  return *reinterpret_cast<u16*>(&h);
}
__device__ __forceinline__ float bf2f(u16 u) {
  __hip_bfloat16 h;
  *reinterpret_cast<u16*>(&h) = u;
  return __bfloat162float(h);
}

// ---------------- K0: zero e[M] and c[B*D] (atomic targets) ----------------
__global__ void k_zero(float* __restrict__ e, float* __restrict__ c) {
  int i = blockIdx.x * 256 + threadIdx.x;   // 65536 threads
  e[i] = 0.f;
  if (i < BB * DD) c[i] = 0.f;
}

// ---------------- K1a: enc f32 -> bf16 (8 elems/thread) ----------------
__global__ void k_cvt(const float* __restrict__ enc, u16* __restrict__ out) {
  long i = (long)blockIdx.x * 256 + threadIdx.x;   // 8M threads
  const f4* ep = (const f4*)enc;
  f4 x = ep[2 * i], y = ep[2 * i + 1];
  u16x8 o;
  o[0] = f2bf(x[0]); o[1] = f2bf(x[1]); o[2] = f2bf(x[2]); o[3] = f2bf(x[3]);
  o[4] = f2bf(y[0]); o[5] = f2bf(y[1]); o[6] = f2bf(y[2]); o[7] = f2bf(y[3]);
  ((u16x8*)out)[i] = o;
}

// ---------------- K1b: W_enc[k][n] -> Wt bf16 [n][k] ----------------
__global__ void k_tw(const float* __restrict__ W, u16* __restrict__ Wt) {
  __shared__ float tile[64][65];
  int k0 = (blockIdx.x & 15) * 64;
  int n0 = (blockIdx.x >> 4) * 64;
  int tid = threadIdx.x;
  for (int i = tid; i < 4096; i += 256) {
    int r = i >> 6, cc = i & 63;
    tile[r][cc] = W[(k0 + r) * 1024 + n0 + cc];
  }
  __syncthreads();
  for (int i = tid; i < 4096; i += 256) {
    int nr = i >> 6, kc = i & 63;
    Wt[(n0 + nr) * 1024 + k0 + kc] = f2bf(tile[kc][nr]);
  }
}

// ---------------- K1c: location conv -> attc[M][10] ----------------
__global__ void k_conv(const float* __restrict__ att_prev, const float* __restrict__ conv_w,
                       float* __restrict__ attc) {
  __shared__ float cw[CC * FW];
  __shared__ float ap[256 + 2 * 100];
  int b = blockIdx.x >> 3;
  int t0 = (blockIdx.x & 7) * 256;
  int tid = threadIdx.x;
  for (int i = tid; i < CC * FW; i += 256) cw[i] = conv_w[i];
  for (int i = tid; i < 456; i += 256) {
    int t = t0 - 100 + i;
    ap[i] = (t >= 0 && t < TT) ? att_prev[b * TT + t] : 0.f;
  }
  __syncthreads();
  float acc[CC];
#pragma unroll
  for (int c = 0; c < CC; ++c) acc[c] = 0.f;
  for (int f = 0; f < FW; ++f) {
    float x = ap[tid + f];
#pragma unroll
    for (int c = 0; c < CC; ++c) acc[c] += x * cw[c * FW + f];
  }
  int t = t0 + tid;
  float* o = attc + (size_t)(b * TT + t) * CC;
#pragma unroll
  for (int c = 0; c < CC; ++c) o[c] = acc[c];
}

// ---------------- K1d: dec_proj[b][d] = dec_z @ W_dec ----------------
__global__ void k_decp(const float* __restrict__ dec_z, const float* __restrict__ W_dec,
                       float* __restrict__ decp) {
  int b = blockIdx.x >> 2, dc = blockIdx.x & 3;
  __shared__ float z[1024];
  for (int i = threadIdx.x; i < 1024; i += 256) z[i] = dec_z[(b << 10) + i];
  __syncthreads();
  int d = (dc << 8) + threadIdx.x;
  float a0 = 0, a1 = 0, a2 = 0, a3 = 0;
  for (int k = 0; k < 1024; k += 4) {
    a0 += z[k + 0] * W_dec[(k + 0) * 1024 + d];
    a1 += z[k + 1] * W_dec[(k + 1) * 1024 + d];
    a2 += z[k + 2] * W_dec[(k + 2) * 1024 + d];
    a3 += z[k + 3] * W_dec[(k + 3) * 1024 + d];
  }
  decp[(b << 10) + d] = (a0 + a1) + (a2 + a3);
}

// ---------------- K2: fused bf16 GEMM + loc/dec/bias + tanh + gvec-dot -> e ----
// 128x128 tile, BK=32, 4 waves (2x2 of 64x64), mfma_f32_16x16x32_bf16.
// A[M][K] bf16 row-major; Bt[N][K] bf16 (W_enc transposed) -> both tiles are
// [128 rows][32 k] bf16 in LDS, staged by global_load_lds width 16 with an
// XOR chunk swizzle (p = (kg + (row>>1)) & 3) -> 2-way-max bank conflicts.
__global__ __launch_bounds__(256, 2) void k_gemm(
    const u16* __restrict__ A, const u16* __restrict__ Bt,
    const float* __restrict__ benc, const float* __restrict__ decp,
    const float* __restrict__ attc, const float* __restrict__ watt,
    const float* __restrict__ gvec, float* __restrict__ e) {
  __shared__ u16 sA[2][128 * 32];
  __shared__ u16 sB[2][128 * 32];
  __shared__ float s_col[128];
  __shared__ float s_g[128];
  __shared__ float s_watt[CC * 128];
  __shared__ float s_attc[128 * CC];
  __shared__ float s_ep[128][2];

  int tid = threadIdx.x;
  int w = tid >> 6, lane = tid & 63;
  // XCD-grouped order: hw block i runs orig = (i%8)*512 + i/8, so each XCD's
  // L2 sees 64 consecutive m-groups x all 8 n-blocks (A-tile reuse in L2).
  int orig = ((blockIdx.x & 7) << 9) + (blockIdx.x >> 3);
  int bm = orig >> 3, bn = orig & 7;
  int brow = bm << 7;
  int bcol = bn << 7;
  int b = brow >> 11;   // batch index (tile never crosses batch: 2048 % 128 == 0)

  // epilogue operands (small, independent of main loop)
  if (tid < 128) {
    s_col[tid] = benc[bcol + tid] + decp[(b << 10) + bcol + tid];
    s_g[tid] = gvec[bcol + tid];
    s_ep[tid][0] = 0.f;
    s_ep[tid][1] = 0.f;
  }
  for (int i = tid; i < CC * 128; i += 256) {
    int c = i >> 7, d = i & 127;
    s_watt[c * 128 + d] = watt[c * 1024 + bcol + d];
  }
  for (int i = tid; i < 128 * CC; i += 256)
    s_attc[i] = attc[(size_t)brow * CC + i];

  f32x4 acc[4][4];
#pragma unroll
  for (int i = 0; i < 4; ++i)
#pragma unroll
    for (int j = 0; j < 4; ++j) acc[i][j] = (f32x4){0.f, 0.f, 0.f, 0.f};

  int wm = w >> 1, wn = w & 1;
  int frl = lane & 15, fkg = lane >> 4;

  auto stage = [&](int buf, int kt) {
    int k0 = kt << 5;
#pragma unroll
    for (int q = 0; q < 2; ++q) {
      int ci = (q << 8) + (w << 6) + lane;
      int row = ci >> 2, p = ci & 3;
      int kg = (p - (row >> 1)) & 3;            // inverse swizzle on the source
      const u16* ga = A + (size_t)(brow + row) * 1024 + k0 + (kg << 3);
      u16* la = &sA[buf][((q << 8) + (w << 6)) << 3];   // wave-uniform base
      __builtin_amdgcn_global_load_lds(
          (const __attribute__((address_space(1))) void*)ga,
          (__attribute__((address_space(3))) void*)la, 16, 0, 0);
      const u16* gb = Bt + (size_t)(bcol + row) * 1024 + k0 + (kg << 3);
      u16* lb = &sB[buf][((q << 8) + (w << 6)) << 3];
      __builtin_amdgcn_global_load_lds(
          (const __attribute__((address_space(1))) void*)gb,
          (__attribute__((address_space(3))) void*)lb, 16, 0, 0);
    }
  };

  stage(0, 0);
  __syncthreads();   // drains vmcnt before barrier (compiler-enforced)

  for (int kt = 0; kt < 32; ++kt) {
    int cur = kt & 1;
    if (kt < 31) stage(cur ^ 1, kt + 1);
    short8 af[4], bfr[4];
#pragma unroll
    for (int mi = 0; mi < 4; ++mi) {
      int r = (wm << 6) + (mi << 4) + frl;
      int p = (fkg + (r >> 1)) & 3;             // swizzled read
      af[mi] = *(const short8*)&sA[cur][(r << 5) + (p << 3)];
    }
#pragma unroll
    for (int ni = 0; ni < 4; ++ni) {
      int r = (wn << 6) + (ni << 4) + frl;
      int p = (fkg + (r >> 1)) & 3;
      bfr[ni] = *(const short8*)&sB[cur][(r << 5) + (p << 3)];
    }
#pragma unroll
    for (int mi = 0; mi < 4; ++mi)
#pragma unroll
      for (int ni = 0; ni < 4; ++ni)
        acc[mi][ni] = __builtin_amdgcn_mfma_f32_16x16x32_bf16(af[mi], bfr[ni], acc[mi][ni], 0, 0, 0);
    __syncthreads();
  }

  // Epilogue: q = acc + b_enc + dec_proj + loc; e_partial = sum_d g[d]*tanh(q)
  // D layout: col = lane&15, row = (lane>>4)*4 + j   [m89-verified]
#pragma unroll
  for (int mi = 0; mi < 4; ++mi) {
#pragma unroll
    for (int j = 0; j < 4; ++j) {
      int rl = (wm << 6) + (mi << 4) + (fkg << 2) + j;
      float ar[CC];
#pragma unroll
      for (int c = 0; c < CC; ++c) ar[c] = s_attc[rl * CC + c];
      float esum = 0.f;
#pragma unroll
      for (int ni = 0; ni < 4; ++ni) {
        int col = (wn << 6) + (ni << 4) + frl;
        float qv = acc[mi][ni][j] + s_col[col];
#pragma unroll
        for (int c = 0; c < CC; ++c) qv += ar[c] * s_watt[c * 128 + col];
        esum += s_g[col] * tanhf(qv);
      }
#pragma unroll
      for (int o = 8; o >= 1; o >>= 1) esum += __shfl_xor(esum, o, 16);
      if (frl == 0) s_ep[rl][wn] = esum;
    }
  }
  __syncthreads();
  if (tid < 128) atomicAdd(&e[brow + tid], s_ep[tid][0] + s_ep[tid][1]);
}

// ---------------- K3: masked softmax(2*e) -> w ----------------
__global__ __launch_bounds__(256) void k_softmax(const float* __restrict__ e,
                                                 const int* __restrict__ len,
                                                 float* __restrict__ wout) {
  int b = blockIdx.x;
  int L = len[b];
  const float* eb = e + b * TT;
  __shared__ float red[4], red2[4];
  int tid = threadIdx.x, w = tid >> 6, lane = tid & 63;
  float m = -3.4e38f;
  for (int t = tid; t < TT; t += 256)
    if (t < L) m = fmaxf(m, eb[t]);
  for (int o = 32; o >= 1; o >>= 1) m = fmaxf(m, __shfl_xor(m, o, 64));
  if (lane == 0) red[w] = m;
  __syncthreads();
  m = fmaxf(fmaxf(red[0], red[1]), fmaxf(red[2], red[3]));
  float s = 0.f;
  for (int t = tid; t < TT; t += 256)
    if (t < L) s += __expf(2.f * (eb[t] - m));
  for (int o = 32; o >= 1; o >>= 1) s += __shfl_xor(s, o, 64);
  if (lane == 0) red2[w] = s;
  __syncthreads();
  s = red2[0] + red2[1] + red2[2] + red2[3];
  float inv = 1.f / s;
  for (int t = tid; t < TT; t += 256)
    wout[b * TT + t] = (t < L) ? __expf(2.f * (eb[t] - m)) * inv : 0.f;
}

// ---------------- K4: c[b][d] = sum_t w[b][t] * enc[b][t][d] ----------------
__global__ __launch_bounds__(256) void k_ctx(const u16* __restrict__ encbf,
                                             const float* __restrict__ wout,
                                             float* __restrict__ c) {
  int bid = blockIdx.x;           // 32 b * 4 echunk * 8 tchunk
  int b = bid >> 5;
  int ec = (bid >> 3) & 3;
  int tc = bid & 7;
  int col = (ec << 8) + threadIdx.x;
  const u16* eb = encbf + ((size_t)(b * TT + tc * 256) << 10) + col;
  const float* wb = wout + b * TT + tc * 256;
  float a0 = 0, a1 = 0, a2 = 0, a3 = 0;
  for (int t = 0; t < 256; t += 4) {
    a0 += wb[t + 0] * bf2f(eb[(size_t)(t + 0) << 10]);
    a1 += wb[t + 1] * bf2f(eb[(size_t)(t + 1) << 10]);
    a2 += wb[t + 2] * bf2f(eb[(size_t)(t + 2) << 10]);
    a3 += wb[t + 3] * bf2f(eb[(size_t)(t + 3) << 10]);
  }
  atomicAdd(&c[(b << 10) + col], (a0 + a1) + (a2 + a3));
}

extern "C" void kernel_launch(void* const* d_in, const int* in_sizes, int n_in,
                              void* d_out, int out_size, void* d_ws, size_t ws_size,
                              hipStream_t stream) {
  const float* enc = (const float*)d_in[0];
  const int* elen = (const int*)d_in[1];
  const float* dec_z = (const float*)d_in[2];
  const float* att_prev = (const float*)d_in[3];
  const float* W_enc = (const float*)d_in[4];
  const float* b_enc = (const float*)d_in[5];
  const float* W_dec = (const float*)d_in[6];
  const float* W_att = (const float*)d_in[7];
  const float* conv_w = (const float*)d_in[8];
  const float* gvec_w = (const float*)d_in[9];
  // gvec_b shifts all logits equally -> cancels in softmax; e itself not returned.

  char* ws = (char*)d_ws;
  u16* encbf = (u16*)ws;  ws += (size_t)MM * EE * 2;       // 128 MB
  u16* Wt = (u16*)ws;     ws += (size_t)EE * DD * 2;       // 2 MB
  float* attc = (float*)ws; ws += (size_t)MM * CC * 4;     // 2.6 MB
  float* decp = (float*)ws; ws += (size_t)BB * DD * 4;
  float* e = (float*)ws;    ws += (size_t)MM * 4;

  float* c = (float*)d_out;            // [32][1024]
  float* wout = c + BB * DD;           // [32][2048]

  k_zero<<<256, 256, 0, stream>>>(e, c);
  k_cvt<<<(MM * EE / 8) / 256, 256, 0, stream>>>(enc, encbf);
  k_tw<<<256, 256, 0, stream>>>(W_enc, Wt);
  k_conv<<<256, 256, 0, stream>>>(att_prev, conv_w, attc);
  k_decp<<<128, 256, 0, stream>>>(dec_z, W_dec, decp);
  k_gemm<<<4096, 256, 0, stream>>>(encbf, Wt, b_enc, decp, attc, W_att, gvec_w, e);
  k_softmax<<<BB, 256, 0, stream>>>(e, elen, wout);
  k_ctx<<<1024, 256, 0, stream>>>(encbf, wout, c);
}

// Round 2
// 715.072 us; speedup vs baseline: 1.0243x; 1.0243x over previous
//
#include <hip/hip_runtime.h>
#include <hip/hip_bf16.h>
#include <math.h>

// Problem constants
#define BB 32
#define TT 2048
#define EE 1024
#define DD 1024
#define MM (BB * TT)   // 65536 rows
#define CC 10
#define FW 201

typedef __attribute__((ext_vector_type(8))) short short8;
typedef __attribute__((ext_vector_type(4))) float f32x4;
typedef __attribute__((ext_vector_type(4))) float f4;
typedef __attribute__((ext_vector_type(8))) unsigned short u16x8;
typedef unsigned short u16;

__device__ __forceinline__ u16 f2bf(float f) {
  __hip_bfloat16 h = __float2bfloat16(f);
  return *reinterpret_cast<u16*>(&h);
}
__device__ __forceinline__ float bf2f(u16 u) {
  __hip_bfloat16 h;
  *reinterpret_cast<u16*>(&h) = u;
  return __bfloat162float(h);
}
__device__ __forceinline__ float tanh_fast(float x) {
  // tanh(x) = 1 - 2/(exp(2x)+1); exact at +-inf, ~1e-6 ulp err via v_exp/v_rcp
  float ex = __expf(2.f * x);
  return 1.f - 2.f * __builtin_amdgcn_rcpf(ex + 1.f);
}

// ---------------- K0: zero c (atomic target of k_ctx) ----------------
__global__ void k_zero(float* __restrict__ c) {
  int i = blockIdx.x * 256 + threadIdx.x;   // 32768
  c[i] = 0.f;
}

// ---------------- K1a: enc f32 -> bf16 (8 elems/thread) ----------------
__global__ void k_cvt(const float* __restrict__ enc, u16* __restrict__ out) {
  long i = (long)blockIdx.x * 256 + threadIdx.x;   // 8M threads
  const f4* ep = (const f4*)enc;
  f4 x = ep[2 * i], y = ep[2 * i + 1];
  u16x8 o;
  o[0] = f2bf(x[0]); o[1] = f2bf(x[1]); o[2] = f2bf(x[2]); o[3] = f2bf(x[3]);
  o[4] = f2bf(y[0]); o[5] = f2bf(y[1]); o[6] = f2bf(y[2]); o[7] = f2bf(y[3]);
  ((u16x8*)out)[i] = o;
}

// ---------------- K1b: W_enc[k][n] -> Wt bf16 [n][k] ----------------
__global__ void k_tw(const float* __restrict__ W, u16* __restrict__ Wt) {
  __shared__ float tile[64][65];
  int k0 = (blockIdx.x & 15) * 64;
  int n0 = (blockIdx.x >> 4) * 64;
  int tid = threadIdx.x;
  for (int i = tid; i < 4096; i += 256) {
    int r = i >> 6, cc = i & 63;
    tile[r][cc] = W[(k0 + r) * 1024 + n0 + cc];
  }
  __syncthreads();
  for (int i = tid; i < 4096; i += 256) {
    int nr = i >> 6, kc = i & 63;
    Wt[(n0 + nr) * 1024 + k0 + kc] = f2bf(tile[kc][nr]);
  }
}

// ---------------- K1c: location conv -> attc[M][10] ----------------
__global__ void k_conv(const float* __restrict__ att_prev, const float* __restrict__ conv_w,
                       float* __restrict__ attc) {
  __shared__ float cw[CC * FW];
  __shared__ float ap[256 + 2 * 100];
  int b = blockIdx.x >> 3;
  int t0 = (blockIdx.x & 7) * 256;
  int tid = threadIdx.x;
  for (int i = tid; i < CC * FW; i += 256) cw[i] = conv_w[i];
  for (int i = tid; i < 456; i += 256) {
    int t = t0 - 100 + i;
    ap[i] = (t >= 0 && t < TT) ? att_prev[b * TT + t] : 0.f;
  }
  __syncthreads();
  float acc[CC];
#pragma unroll
  for (int c = 0; c < CC; ++c) acc[c] = 0.f;
  for (int f = 0; f < FW; ++f) {
    float x = ap[tid + f];
#pragma unroll
    for (int c = 0; c < CC; ++c) acc[c] += x * cw[c * FW + f];
  }
  int t = t0 + tid;
  float* o = attc + (size_t)(b * TT + t) * CC;
#pragma unroll
  for (int c = 0; c < CC; ++c) o[c] = acc[c];
}

// ---------------- K1d: dec_proj = dec_z @ W_dec (k-parallel) ----------------
__global__ __launch_bounds__(256) void k_decp(const float* __restrict__ dec_z,
                                              const float* __restrict__ W_dec,
                                              float* __restrict__ decp) {
  int b = blockIdx.x >> 4;          // 32 b
  int c0 = (blockIdx.x & 15) << 6;  // 16 chunks of 64 cols
  __shared__ float z[1024];
  __shared__ float red[4][64];
  for (int i = threadIdx.x; i < 1024; i += 256) z[i] = dec_z[(b << 10) + i];
  __syncthreads();
  int d = c0 + (threadIdx.x & 63), ks = threadIdx.x >> 6;
  float a = 0.f;
  const float* Wp = W_dec + (size_t)(ks << 8) * 1024 + d;
  const float* zp = z + (ks << 8);
#pragma unroll 4
  for (int k = 0; k < 256; ++k) a += zp[k] * Wp[(size_t)k * 1024];
  red[ks][threadIdx.x & 63] = a;
  __syncthreads();
  if (threadIdx.x < 64)
    decp[(b << 10) + c0 + threadIdx.x] =
        (red[0][threadIdx.x] + red[1][threadIdx.x]) + (red[2][threadIdx.x] + red[3][threadIdx.x]);
}

// ---------------- K2: 256x256 8-phase bf16 GEMM + fused tanh/gvec epilogue ----
// Tiles: BM=BN=256, BK=64, 16 K-tiles, 8 waves (2m x 4n), 512 threads.
// LDS: per matrix 4 k-half slots [tile-parity][kk] of 256 rows x 32 k bf16
// (16KB each) -> 128KB total, ring-rotated at half-tile granularity.
// Schedule (iter I computes tiles t=2I, t+1; phases p1..p8):
//   reads:  p1 t.k0.CH0  p2 t.k0.CH1  p3 t.k1.CH0  p4 t.k1.CH1
//           p5 t1.k0.CH0 p6 t1.k0.CH1 p7 t1.k1.CH0 p8 t1.k1.CH1
//   stage:  p1 t1.Ak1  p2 t1.Bk1  p3 t2.Ak0  p4 t2.Bk0
//           p5 t2.Ak1  p6 t2.Bk1  p7 t3.Ak0  p8 t3.Bk0
//   waits:  vmcnt(8) at p2,p4,p6,p8 (4 halves x 2 loads in flight max).
// Every stage targets a slot whose last reader finished >=1 phase earlier
// (A slots die at CH1 phases, B slots at CH0 phases); every read is covered
// by the vmcnt two phases earlier + barrier. Last iter drains 8->4->0.
#define VM8 asm volatile("s_waitcnt vmcnt(8)" ::: "memory")
#define VM4 asm volatile("s_waitcnt vmcnt(4)" ::: "memory")
#define VM0 asm volatile("s_waitcnt vmcnt(0)" ::: "memory")

__global__ __launch_bounds__(512, 2) void k_gemm8(
    const u16* __restrict__ A, const u16* __restrict__ Bt,
    const float* __restrict__ benc, const float* __restrict__ decp,
    const float* __restrict__ attc, const float* __restrict__ watt,
    const float* __restrict__ gvec, float* __restrict__ epart) {
  extern __shared__ u16 smem[];
  u16* sA = smem;               // [par][kk][256*32]
  u16* sB = smem + 32768;

  int tid = threadIdx.x;
  int lane = tid & 63, wid = tid >> 6;
  int frl = lane & 15, fkg = lane >> 4;
  int wm = wid >> 2, wn = wid & 3;

  // XCD-grouped block order (nwg=1024, 8 XCDs, 128 blocks per XCD chunk)
  int orig = (blockIdx.x & 7) * 128 + (blockIdx.x >> 3);
  int bm = orig >> 2, bn = orig & 3;
  int brow = bm << 8;            // 256-row panel
  int bcol = bn << 8;            // 256-col panel
  int b = brow >> 11;            // batch (256 | 2048 -> tile within one batch)

  auto stA = [&](int par, int kk, int tile) {
    u16* region = sA + ((par * 2 + kk) << 13);
    const u16* gb = A + (size_t)brow * 1024 + tile * 64 + kk * 32;
#pragma unroll
    for (int q = 0; q < 2; ++q) {
      int s = (q << 9) + tid;
      int r = s >> 2, ch = s & 3;
      int cs = ch ^ ((r >> 1) & 3);           // inverse swizzle on source
      const u16* src = gb + (size_t)r * 1024 + (cs << 3);
      u16* dst = region + (((q << 9) + (tid & ~63)) << 3);  // wave-uniform
      __builtin_amdgcn_global_load_lds(
          (const __attribute__((address_space(1))) void*)src,
          (__attribute__((address_space(3))) void*)dst, 16, 0, 0);
    }
  };
  auto stB = [&](int par, int kk, int tile) {
    u16* region = sB + ((par * 2 + kk) << 13);
    const u16* gb = Bt + (size_t)bcol * 1024 + tile * 64 + kk * 32;
#pragma unroll
    for (int q = 0; q < 2; ++q) {
      int s = (q << 9) + tid;
      int r = s >> 2, ch = s & 3;
      int cs = ch ^ ((r >> 1) & 3);
      const u16* src = gb + (size_t)r * 1024 + (cs << 3);
      u16* dst = region + (((q << 9) + (tid & ~63)) << 3);
      __builtin_amdgcn_global_load_lds(
          (const __attribute__((address_space(1))) void*)src,
          (__attribute__((address_space(3))) void*)dst, 16, 0, 0);
    }
  };
  auto rdA = [&](int par, int kk, int mi) -> short8 {
    int row = (wm << 7) + (mi << 4) + frl;
    int g = fkg ^ ((row >> 1) & 3);           // swizzled read
    return *(const short8*)(sA + ((par * 2 + kk) << 13) + (row << 5) + (g << 3));
  };
  auto rdB = [&](int par, int kk, int ni) -> short8 {
    int row = (wn << 6) + (ni << 4) + frl;
    int g = fkg ^ ((row >> 1) & 3);
    return *(const short8*)(sB + ((par * 2 + kk) << 13) + (row << 5) + (g << 3));
  };

  f32x4 acc[8][4];
#pragma unroll
  for (int i = 0; i < 8; ++i)
#pragma unroll
    for (int j = 0; j < 4; ++j) acc[i][j] = (f32x4){0.f, 0.f, 0.f, 0.f};
  short8 afr[4], bfr[4];

#define PH(PAR, KK, CH, STAGE, WAIT)                                          \
  {                                                                           \
    if ((CH) == 0) {                                                          \
      _Pragma("unroll") for (int ni = 0; ni < 4; ++ni)                        \
          bfr[ni] = rdB(PAR, KK, ni);                                         \
    }                                                                         \
    _Pragma("unroll") for (int i = 0; i < 4; ++i)                             \
        afr[i] = rdA(PAR, KK, (CH)*4 + i);                                    \
    STAGE;                                                                    \
    WAIT;                                                                     \
    __builtin_amdgcn_s_barrier();                                             \
    __builtin_amdgcn_s_setprio(1);                                            \
    _Pragma("unroll") for (int i = 0; i < 4; ++i)                             \
        _Pragma("unroll") for (int ni = 0; ni < 4; ++ni)                      \
            acc[(CH)*4 + i][ni] = __builtin_amdgcn_mfma_f32_16x16x32_bf16(    \
                afr[i], bfr[ni], acc[(CH)*4 + i][ni], 0, 0, 0);               \
    __builtin_amdgcn_s_setprio(0);                                            \
    __builtin_amdgcn_s_barrier();                                             \
  }

  // Prologue: t0.Ak0 t0.Bk0 t0.Ak1 t0.Bk1 t1.Ak0 t1.Bk0 (6 halves, 12 loads)
  stA(0, 0, 0); stB(0, 0, 0);
  stA(0, 1, 0); stB(0, 1, 0);
  stA(1, 0, 1); stB(1, 0, 1);
  VM8;                           // first 2 halves (t0 k0) landed
  __builtin_amdgcn_s_barrier();

#pragma unroll 1
  for (int I = 0; I < 7; ++I) {
    int t = 2 * I;
    PH(0, 0, 0, stA(1, 1, t + 1), ((void)0));
    PH(0, 0, 1, stB(1, 1, t + 1), VM8);
    PH(0, 1, 0, stA(0, 0, t + 2), ((void)0));
    PH(0, 1, 1, stB(0, 0, t + 2), VM8);
    PH(1, 0, 0, stA(0, 1, t + 2), ((void)0));
    PH(1, 0, 1, stB(0, 1, t + 2), VM8);
    PH(1, 1, 0, stA(1, 0, t + 3), ((void)0));
    PH(1, 1, 1, stB(1, 0, t + 3), VM8);
  }
  // Final iteration (tiles 14,15): no further stages, drain 8 -> 4 -> 0.
  PH(0, 0, 0, stA(1, 1, 15), ((void)0));
  PH(0, 0, 1, stB(1, 1, 15), VM8);
  PH(0, 1, 0, ((void)0), ((void)0));
  PH(0, 1, 1, ((void)0), VM4);
  PH(1, 0, 0, ((void)0), ((void)0));
  PH(1, 0, 1, ((void)0), VM0);
  PH(1, 1, 0, ((void)0), ((void)0));
  PH(1, 1, 1, ((void)0), ((void)0));
#undef PH

  // ---- Epilogue: reuse sA LDS for small tables ----
  __syncthreads();
  float* fsm = (float*)smem;
  float* se_attc = fsm;              // 2560
  float* se_watt = fsm + 2560;       // 2560
  float* se_col  = fsm + 5120;       // 256
  float* se_g    = fsm + 5376;       // 256
  float* se_ep   = fsm + 5632;       // 256*4
  for (int i = tid; i < 2560; i += 512) {
    se_attc[i] = attc[(size_t)brow * 10 + i];
    se_watt[i] = watt[(i >> 8) * 1024 + bcol + (i & 255)];
  }
  if (tid < 256) {
    se_col[tid] = benc[bcol + tid] + decp[(b << 10) + bcol + tid];
    se_g[tid] = gvec[bcol + tid];
  }
  __syncthreads();

#pragma unroll
  for (int mi = 0; mi < 8; ++mi) {
#pragma unroll
    for (int j = 0; j < 4; ++j) {
      int rl = (wm << 7) + (mi << 4) + (fkg << 2) + j;
      float ar[CC];
#pragma unroll
      for (int c = 0; c < CC; ++c) ar[c] = se_attc[rl * 10 + c];
      float esum = 0.f;
#pragma unroll
      for (int ni = 0; ni < 4; ++ni) {
        int cl = (wn << 6) + (ni << 4) + frl;
        float qv = acc[mi][ni][j] + se_col[cl];
#pragma unroll
        for (int c = 0; c < CC; ++c) qv += ar[c] * se_watt[c * 256 + cl];
        esum += se_g[cl] * tanh_fast(qv);
      }
#pragma unroll
      for (int o = 8; o >= 1; o >>= 1) esum += __shfl_xor(esum, o, 16);
      if (frl == 0) se_ep[rl * 4 + wn] = esum;
    }
  }
  __syncthreads();
  if (tid < 256)
    epart[bn * MM + brow + tid] =
        (se_ep[tid * 4 + 0] + se_ep[tid * 4 + 1]) + (se_ep[tid * 4 + 2] + se_ep[tid * 4 + 3]);
}

// ---------------- K3: masked softmax(2*e) over 4 partial slabs ----------------
__global__ __launch_bounds__(256) void k_softmax(const float* __restrict__ ep,
                                                 const int* __restrict__ len,
                                                 float* __restrict__ wout) {
  int b = blockIdx.x;
  int L = len[b];
  __shared__ float se[TT];
  __shared__ float red[4], red2[4];
  int tid = threadIdx.x, w = tid >> 6, lane = tid & 63;
  for (int t = tid; t < TT; t += 256) {
    int m = b * TT + t;
    se[t] = (ep[m] + ep[MM + m]) + (ep[2 * MM + m] + ep[3 * MM + m]);
  }
  __syncthreads();
  float mx = -3.4e38f;
  for (int t = tid; t < TT; t += 256)
    if (t < L) mx = fmaxf(mx, se[t]);
  for (int o = 32; o >= 1; o >>= 1) mx = fmaxf(mx, __shfl_xor(mx, o, 64));
  if (lane == 0) red[w] = mx;
  __syncthreads();
  mx = fmaxf(fmaxf(red[0], red[1]), fmaxf(red[2], red[3]));
  float s = 0.f;
  for (int t = tid; t < TT; t += 256)
    if (t < L) s += __expf(2.f * (se[t] - mx));
  for (int o = 32; o >= 1; o >>= 1) s += __shfl_xor(s, o, 64);
  if (lane == 0) red2[w] = s;
  __syncthreads();
  s = (red2[0] + red2[1]) + (red2[2] + red2[3]);
  float inv = 1.f / s;
  for (int t = tid; t < TT; t += 256)
    wout[b * TT + t] = (t < L) ? __expf(2.f * (se[t] - mx)) * inv : 0.f;
}

// ---------------- K4: c[b][d] = sum_t w[b][t] * enc[b][t][d] (short8) --------
__global__ __launch_bounds__(256) void k_ctx(const u16* __restrict__ encbf,
                                             const float* __restrict__ wout,
                                             float* __restrict__ c) {
  int b = blockIdx.x >> 3;
  int t0 = (blockIdx.x & 7) << 8;
  int col8 = (threadIdx.x & 127) << 3;
  int rp = threadIdx.x >> 7;
  const float* wb = wout + b * TT + t0;
  float acc[8] = {0, 0, 0, 0, 0, 0, 0, 0};
  for (int tt = rp; tt < 256; tt += 2) {
    float wv = wb[tt];
    if (wv == 0.f) continue;     // wave-uniform skip of masked tail
    u16x8 v = *(const u16x8*)(encbf + (((size_t)(b * TT + t0 + tt)) << 10) + col8);
#pragma unroll
    for (int j = 0; j < 8; ++j) acc[j] += wv * bf2f(v[j]);
  }
  __shared__ float red[128][8];
  if (rp) {
#pragma unroll
    for (int j = 0; j < 8; ++j) red[threadIdx.x & 127][j] = acc[j];
  }
  __syncthreads();
  if (!rp) {
#pragma unroll
    for (int j = 0; j < 8; ++j) acc[j] += red[threadIdx.x][j];
#pragma unroll
    for (int j = 0; j < 8; ++j) atomicAdd(&c[(b << 10) + col8 + j], acc[j]);
  }
}

extern "C" void kernel_launch(void* const* d_in, const int* in_sizes, int n_in,
                              void* d_out, int out_size, void* d_ws, size_t ws_size,
                              hipStream_t stream) {
  const float* enc = (const float*)d_in[0];
  const int* elen = (const int*)d_in[1];
  const float* dec_z = (const float*)d_in[2];
  const float* att_prev = (const float*)d_in[3];
  const float* W_enc = (const float*)d_in[4];
  const float* b_enc = (const float*)d_in[5];
  const float* W_dec = (const float*)d_in[6];
  const float* W_att = (const float*)d_in[7];
  const float* conv_w = (const float*)d_in[8];
  const float* gvec_w = (const float*)d_in[9];
  // gvec_b shifts all logits equally -> cancels in softmax.

  char* ws = (char*)d_ws;
  u16* encbf = (u16*)ws;    ws += (size_t)MM * EE * 2;     // 128 MB
  u16* Wt = (u16*)ws;       ws += (size_t)EE * DD * 2;     // 2 MB
  float* attc = (float*)ws; ws += (size_t)MM * CC * 4;     // 2.6 MB
  float* decp = (float*)ws; ws += (size_t)BB * DD * 4;
  float* ep = (float*)ws;   ws += (size_t)4 * MM * 4;      // 4 partial slabs

  float* c = (float*)d_out;            // [32][1024]
  float* wout = c + BB * DD;           // [32][2048]

  hipFuncSetAttribute((const void*)k_gemm8,
                      hipFuncAttributeMaxDynamicSharedMemorySize, 131072);

  k_zero<<<128, 256, 0, stream>>>(c);
  k_cvt<<<(MM * EE / 8) / 256, 256, 0, stream>>>(enc, encbf);
  k_tw<<<256, 256, 0, stream>>>(W_enc, Wt);
  k_conv<<<256, 256, 0, stream>>>(att_prev, conv_w, attc);
  k_decp<<<512, 256, 0, stream>>>(dec_z, W_dec, decp);
  k_gemm8<<<1024, 512, 131072, stream>>>(encbf, Wt, b_enc, decp, attc, W_att, gvec_w, ep);
  k_softmax<<<BB, 256, 0, stream>>>(ep, elen, wout);
  k_ctx<<<256, 256, 0, stream>>>(encbf, wout, c);
}

// Round 3
// 618.969 us; speedup vs baseline: 1.1834x; 1.1553x over previous
//
#include <hip/hip_runtime.h>
#include <hip/hip_bf16.h>
#include <math.h>

// Problem constants
#define BB 32
#define TT 2048
#define EE 1024
#define DD 1024
#define MM (BB * TT)   // 65536 rows
#define CC 10
#define FW 201

typedef __attribute__((ext_vector_type(8))) short short8;
typedef __attribute__((ext_vector_type(4))) float f32x4;
typedef __attribute__((ext_vector_type(4))) float f4;
typedef __attribute__((ext_vector_type(8))) unsigned short u16x8;
typedef __attribute__((ext_vector_type(4))) unsigned int u32x4;
typedef unsigned short u16;
typedef unsigned int u32;

__device__ __forceinline__ u16 f2bf(float f) {
  __hip_bfloat16 h = __float2bfloat16(f);
  return *reinterpret_cast<u16*>(&h);
}
__device__ __forceinline__ float bf2f(u16 u) {
  __hip_bfloat16 h;
  *reinterpret_cast<u16*>(&h) = u;
  return __bfloat162float(h);
}
__device__ __forceinline__ u32 cvt_pk_bf16(float lo, float hi) {
  u32 r;
  asm("v_cvt_pk_bf16_f32 %0, %1, %2" : "=v"(r) : "v"(lo), "v"(hi));
  return r;
}
__device__ __forceinline__ float tanh_fast(float x) {
  float ex = __expf(2.f * x);
  return 1.f - 2.f * __builtin_amdgcn_rcpf(ex + 1.f);
}

// ---------------- K_prep: cvt | tw | conv | decp | zero-c | wattT ----------
// block ranges: [0,4096) cvt, [4096,4352) tw, [4352,4608) conv,
//               [4608,5120) decp, [5120,5248) zero-c, [5248,5264) wattT
__global__ __launch_bounds__(256) void k_prep(
    const float* __restrict__ enc, u16* __restrict__ encbf,
    const float* __restrict__ W_enc, u16* __restrict__ Wt,
    const float* __restrict__ att_prev, const float* __restrict__ conv_w,
    u16* __restrict__ attc32,
    const float* __restrict__ dec_z, const float* __restrict__ W_dec,
    float* __restrict__ decp,
    const float* __restrict__ W_att, u16* __restrict__ wattT,
    float* __restrict__ c) {
  int bid = blockIdx.x, tid = threadIdx.x;
  __shared__ float tile[64][65];          // tw
  __shared__ float cw[CC * FW];           // conv
  __shared__ float ap[256 + 2 * 100];     // conv
  __shared__ float z[1024];               // decp
  __shared__ float red[4][64];            // decp

  if (bid < 4096) {
    // ---- enc f32 -> bf16, packed cvt, grid-stride (8M u16x8 chunks) ----
    const f4* ep = (const f4*)enc;
    u32x4* op = (u32x4*)encbf;
    for (long i = (long)bid * 256 + tid; i < (long)MM * EE / 8; i += 4096 * 256) {
      f4 x = ep[2 * i], y = ep[2 * i + 1];
      u32x4 o;
      o[0] = cvt_pk_bf16(x[0], x[1]);
      o[1] = cvt_pk_bf16(x[2], x[3]);
      o[2] = cvt_pk_bf16(y[0], y[1]);
      o[3] = cvt_pk_bf16(y[2], y[3]);
      op[i] = o;
    }
  } else if (bid < 4352) {
    // ---- W_enc[k][n] -> Wt bf16 [n][k] ----
    int rel = bid - 4096;
    int k0 = (rel & 15) * 64, n0 = (rel >> 4) * 64;
    for (int i = tid; i < 4096; i += 256) {
      int r = i >> 6, cc = i & 63;
      tile[r][cc] = W_enc[(k0 + r) * 1024 + n0 + cc];
    }
    __syncthreads();
    for (int i = tid; i < 4096; i += 256) {
      int nr = i >> 6, kc = i & 63;
      Wt[(n0 + nr) * 1024 + k0 + kc] = f2bf(tile[kc][nr]);
    }
  } else if (bid < 4608) {
    // ---- location conv -> attc32 bf16 [M][32] (cols 10..31 = 0) ----
    int rel = bid - 4352;
    int b = rel >> 3, t0 = (rel & 7) * 256;
    for (int i = tid; i < CC * FW; i += 256) cw[i] = conv_w[i];
    for (int i = tid; i < 456; i += 256) {
      int t = t0 - 100 + i;
      ap[i] = (t >= 0 && t < TT) ? att_prev[b * TT + t] : 0.f;
    }
    __syncthreads();
    float acc[CC];
#pragma unroll
    for (int cc = 0; cc < CC; ++cc) acc[cc] = 0.f;
    for (int f = 0; f < FW; ++f) {
      float x = ap[tid + f];
#pragma unroll
      for (int cc = 0; cc < CC; ++cc) acc[cc] += x * cw[cc * FW + f];
    }
    u16 row[32];
#pragma unroll
    for (int cc = 0; cc < CC; ++cc) row[cc] = f2bf(acc[cc]);
#pragma unroll
    for (int cc = CC; cc < 32; ++cc) row[cc] = 0;
    u16x8* o = (u16x8*)(attc32 + ((size_t)(b * TT + t0 + tid) << 5));
#pragma unroll
    for (int q = 0; q < 4; ++q) o[q] = *(u16x8*)&row[q * 8];
  } else if (bid < 5120) {
    // ---- dec_proj = dec_z @ W_dec ----
    int rel = bid - 4608;
    int b = rel >> 4, c0 = (rel & 15) << 6;
    for (int i = tid; i < 1024; i += 256) z[i] = dec_z[(b << 10) + i];
    __syncthreads();
    int d = c0 + (tid & 63), ks = tid >> 6;
    float a = 0.f;
    const float* Wp = W_dec + (size_t)(ks << 8) * 1024 + d;
    const float* zp = z + (ks << 8);
#pragma unroll 4
    for (int k = 0; k < 256; ++k) a += zp[k] * Wp[(size_t)k * 1024];
    red[ks][tid & 63] = a;
    __syncthreads();
    if (tid < 64)
      decp[(b << 10) + c0 + tid] =
          (red[0][tid] + red[1][tid]) + (red[2][tid] + red[3][tid]);
  } else if (bid < 5248) {
    // ---- zero c ----
    c[(bid - 5120) * 256 + tid] = 0.f;
  } else {
    // ---- W_att[10][1024] -> wattT bf16 [1024][32] (rows k>=10 zero) ----
    int n0 = (bid - 5248) << 6;
    if (tid < 64) {
      int n = n0 + tid;
      u16 row[32];
#pragma unroll
      for (int k = 0; k < CC; ++k) row[k] = f2bf(W_att[k * 1024 + n]);
#pragma unroll
      for (int k = CC; k < 32; ++k) row[k] = 0;
      u16x8* o = (u16x8*)(wattT + ((size_t)n << 5));
#pragma unroll
      for (int q = 0; q < 4; ++q) o[q] = *(u16x8*)&row[q * 8];
    }
  }
}

// ---------------- K2: 256x256 8-phase bf16 GEMM + fused tanh/gvec epilogue ----
// BM=BN=256, BK=64, 16 K-tiles, 8 waves (2m x 4n), 512 threads, 128KB LDS.
// Slot ring [par][kk] (16KB each, k-split halves); stage 1 half (2 loads) per
// phase; counted vmcnt; all steady-state reads formally covered (see waits).
// Tail: rank-32 attc32 x wattT update staged into dead (0,0) slots -> 32 extra
// MFMA replace the old 1280-FMA/1280-LDS-read epilogue loc-loop.
#define VM8 asm volatile("s_waitcnt vmcnt(8)" ::: "memory")
#define VM2 asm volatile("s_waitcnt vmcnt(2)" ::: "memory")
#define VM0 asm volatile("s_waitcnt vmcnt(0)" ::: "memory")

__global__ __launch_bounds__(512, 2) void k_gemm8(
    const u16* __restrict__ A, const u16* __restrict__ Bt,
    const u16* __restrict__ attc32, const u16* __restrict__ wattT,
    const float* __restrict__ benc, const float* __restrict__ decp,
    const float* __restrict__ gvec, float* __restrict__ epart) {
  extern __shared__ u16 smem[];
  u16* sA = smem;               // 4 slots [par*2+kk] of 256x32
  u16* sB = smem + 32768;

  int tid = threadIdx.x;
  int lane = tid & 63, wid = tid >> 6;
  int frl = lane & 15, fkg = lane >> 4;
  int wm = wid >> 2, wn = wid & 3;

  int orig = (blockIdx.x & 7) * 128 + (blockIdx.x >> 3);
  int bm = orig >> 2, bn = orig & 3;
  int brow = bm << 8;
  int bcol = bn << 8;
  int b = brow >> 11;

  // generic half-tile stage: region gets rows [0,256) x 32k of src (strided)
  auto stage = [&](u16* region, const u16* srcbase, int stride) {
#pragma unroll
    for (int q = 0; q < 2; ++q) {
      int s = (q << 9) + tid;
      int r = s >> 2, ch = s & 3;
      int cs = ch ^ ((r >> 1) & 3);           // inverse swizzle on source
      const u16* src = srcbase + (size_t)r * stride + (cs << 3);
      u16* dst = region + (((q << 9) + (tid & ~63)) << 3);  // wave-uniform
      __builtin_amdgcn_global_load_lds(
          (const __attribute__((address_space(1))) void*)src,
          (__attribute__((address_space(3))) void*)dst, 16, 0, 0);
    }
  };
  auto stA = [&](int par, int kk, int tile) {
    stage(sA + ((par * 2 + kk) << 13), A + (size_t)brow * 1024 + tile * 64 + kk * 32, 1024);
  };
  auto stB = [&](int par, int kk, int tile) {
    stage(sB + ((par * 2 + kk) << 13), Bt + (size_t)bcol * 1024 + tile * 64 + kk * 32, 1024);
  };
  auto rdA = [&](int par, int kk, int mi) -> short8 {
    int row = (wm << 7) + (mi << 4) + frl;
    int g = fkg ^ ((row >> 1) & 3);           // swizzled read
    return *(const short8*)(sA + ((par * 2 + kk) << 13) + (row << 5) + (g << 3));
  };
  auto rdB = [&](int par, int kk, int ni) -> short8 {
    int row = (wn << 6) + (ni << 4) + frl;
    int g = fkg ^ ((row >> 1) & 3);
    return *(const short8*)(sB + ((par * 2 + kk) << 13) + (row << 5) + (g << 3));
  };

  f32x4 acc[8][4];
#pragma unroll
  for (int i = 0; i < 8; ++i)
#pragma unroll
    for (int j = 0; j < 4; ++j) acc[i][j] = (f32x4){0.f, 0.f, 0.f, 0.f};
  short8 afr[4], bfr[4];

#define PH(PAR, KK, CH, STAGE, WAIT)                                          \
  {                                                                           \
    if ((CH) == 0) {                                                          \
      _Pragma("unroll") for (int ni = 0; ni < 4; ++ni)                        \
          bfr[ni] = rdB(PAR, KK, ni);                                         \
    }                                                                         \
    _Pragma("unroll") for (int i = 0; i < 4; ++i)                             \
        afr[i] = rdA(PAR, KK, (CH)*4 + i);                                    \
    STAGE;                                                                    \
    WAIT;                                                                     \
    __builtin_amdgcn_s_barrier();                                             \
    __builtin_amdgcn_s_setprio(1);                                            \
    _Pragma("unroll") for (int i = 0; i < 4; ++i)                             \
        _Pragma("unroll") for (int ni = 0; ni < 4; ++ni)                      \
            acc[(CH)*4 + i][ni] = __builtin_amdgcn_mfma_f32_16x16x32_bf16(    \
                afr[i], bfr[ni], acc[(CH)*4 + i][ni], 0, 0, 0);               \
    __builtin_amdgcn_s_setprio(0);                                            \
    __builtin_amdgcn_s_barrier();                                             \
  }

  // Prologue: t0 full + t1 k0 (6 halves, 12 loads)
  stA(0, 0, 0); stB(0, 0, 0);
  stA(0, 1, 0); stB(0, 1, 0);
  stA(1, 0, 1); stB(1, 0, 1);
  VM8;
  __builtin_amdgcn_s_barrier();

#pragma unroll 1
  for (int I = 0; I < 7; ++I) {
    int t = 2 * I;
    PH(0, 0, 0, stA(1, 1, t + 1), ((void)0));
    PH(0, 0, 1, stB(1, 1, t + 1), VM8);
    PH(0, 1, 0, stA(0, 0, t + 2), ((void)0));
    PH(0, 1, 1, stB(0, 0, t + 2), VM8);
    PH(1, 0, 0, stA(0, 1, t + 2), ((void)0));
    PH(1, 0, 1, stB(0, 1, t + 2), VM8);
    PH(1, 1, 0, stA(1, 0, t + 3), ((void)0));
    PH(1, 1, 1, stB(1, 0, t + 3), VM8);
  }
  // Tail (tiles 14,15) + staging of attc/wattT into dead (0,0) slots.
  PH(0, 0, 0, stA(1, 1, 15), ((void)0));
  PH(0, 0, 1, stB(1, 1, 15), VM8);
  PH(0, 1, 0, ((void)0), ((void)0));
  PH(0, 1, 1, ((void)0), VM2);   // drains t15(1,0) before p5 reads it
  PH(1, 0, 0, stage(sA, attc32 + ((size_t)brow << 5), 32), ((void)0));
  PH(1, 0, 1, stage(sB, wattT + ((size_t)bcol << 5), 32), VM2);  // t15(1,1) landed
  PH(1, 1, 0, ((void)0), ((void)0));
  PH(1, 1, 1, ((void)0), VM0);   // attc/watt landed; trailing barrier syncs
#undef PH

  // ---- rank-32 location update: acc += attc32_frag x wattT_frag ----
  {
    short8 a2[8], b2[4];
#pragma unroll
    for (int ni = 0; ni < 4; ++ni) b2[ni] = rdB(0, 0, ni);
#pragma unroll
    for (int mi = 0; mi < 8; ++mi) a2[mi] = rdA(0, 0, mi);
#pragma unroll
    for (int mi = 0; mi < 8; ++mi)
#pragma unroll
      for (int ni = 0; ni < 4; ++ni)
        acc[mi][ni] = __builtin_amdgcn_mfma_f32_16x16x32_bf16(a2[mi], b2[ni], acc[mi][ni], 0, 0, 0);
  }

  // ---- light epilogue: e_part = sum_col g*tanh(acc + benc + decp) ----
  float* se_ep = (float*)(sB + (3 << 13));   // dead (1,1) B slot
  float colv[4], gv[4];
#pragma unroll
  for (int ni = 0; ni < 4; ++ni) {
    int cl = bcol + (wn << 6) + (ni << 4) + frl;
    colv[ni] = benc[cl] + decp[(b << 10) + cl];
    gv[ni] = gvec[cl];
  }
#pragma unroll
  for (int mi = 0; mi < 8; ++mi) {
#pragma unroll
    for (int j = 0; j < 4; ++j) {
      int rl = (wm << 7) + (mi << 4) + (fkg << 2) + j;
      float esum = 0.f;
#pragma unroll
      for (int ni = 0; ni < 4; ++ni)
        esum += gv[ni] * tanh_fast(acc[mi][ni][j] + colv[ni]);
#pragma unroll
      for (int o = 8; o >= 1; o >>= 1) esum += __shfl_xor(esum, o, 16);
      if (frl == 0) se_ep[(rl << 2) + wn] = esum;
    }
  }
  __syncthreads();
  if (tid < 256)
    epart[bn * MM + brow + tid] =
        (se_ep[(tid << 2) + 0] + se_ep[(tid << 2) + 1]) +
        (se_ep[(tid << 2) + 2] + se_ep[(tid << 2) + 3]);
}

// ---------------- K3: masked softmax(2*e) over 4 partial slabs ----------------
__global__ __launch_bounds__(256) void k_softmax(const float* __restrict__ ep,
                                                 const int* __restrict__ len,
                                                 float* __restrict__ wout) {
  int b = blockIdx.x;
  int L = len[b];
  __shared__ float se[TT];
  __shared__ float red[4], red2[4];
  int tid = threadIdx.x, w = tid >> 6, lane = tid & 63;
  for (int t = tid; t < TT; t += 256) {
    int m = b * TT + t;
    se[t] = (ep[m] + ep[MM + m]) + (ep[2 * MM + m] + ep[3 * MM + m]);
  }
  __syncthreads();
  float mx = -3.4e38f;
  for (int t = tid; t < TT; t += 256)
    if (t < L) mx = fmaxf(mx, se[t]);
  for (int o = 32; o >= 1; o >>= 1) mx = fmaxf(mx, __shfl_xor(mx, o, 64));
  if (lane == 0) red[w] = mx;
  __syncthreads();
  mx = fmaxf(fmaxf(red[0], red[1]), fmaxf(red[2], red[3]));
  float s = 0.f;
  for (int t = tid; t < TT; t += 256)
    if (t < L) s += __expf(2.f * (se[t] - mx));
  for (int o = 32; o >= 1; o >>= 1) s += __shfl_xor(s, o, 64);
  if (lane == 0) red2[w] = s;
  __syncthreads();
  s = (red2[0] + red2[1]) + (red2[2] + red2[3]);
  float inv = 1.f / s;
  for (int t = tid; t < TT; t += 256)
    wout[b * TT + t] = (t < L) ? __expf(2.f * (se[t] - mx)) * inv : 0.f;
}

// ---------------- K4: c[b][d] = sum_t w[b][t] * enc[b][t][d] (short8) --------
__global__ __launch_bounds__(256) void k_ctx(const u16* __restrict__ encbf,
                                             const float* __restrict__ wout,
                                             float* __restrict__ c) {
  int b = blockIdx.x >> 4;
  int t0 = (blockIdx.x & 15) << 7;   // 16 chunks of 128 rows
  int col8 = (threadIdx.x & 127) << 3;
  int rp = threadIdx.x >> 7;
  const float* wb = wout + b * TT + t0;
  float acc[8] = {0, 0, 0, 0, 0, 0, 0, 0};
  for (int tt = rp; tt < 128; tt += 2) {
    float wv = wb[tt];
    if (wv == 0.f) continue;     // wave-uniform skip of masked tail
    u16x8 v = *(const u16x8*)(encbf + (((size_t)(b * TT + t0 + tt)) << 10) + col8);
#pragma unroll
    for (int j = 0; j < 8; ++j) acc[j] += wv * bf2f(v[j]);
  }
  __shared__ float red[128][8];
  if (rp) {
#pragma unroll
    for (int j = 0; j < 8; ++j) red[threadIdx.x & 127][j] = acc[j];
  }
  __syncthreads();
  if (!rp) {
#pragma unroll
    for (int j = 0; j < 8; ++j) acc[j] += red[threadIdx.x][j];
#pragma unroll
    for (int j = 0; j < 8; ++j) atomicAdd(&c[(b << 10) + col8 + j], acc[j]);
  }
}

extern "C" void kernel_launch(void* const* d_in, const int* in_sizes, int n_in,
                              void* d_out, int out_size, void* d_ws, size_t ws_size,
                              hipStream_t stream) {
  const float* enc = (const float*)d_in[0];
  const int* elen = (const int*)d_in[1];
  const float* dec_z = (const float*)d_in[2];
  const float* att_prev = (const float*)d_in[3];
  const float* W_enc = (const float*)d_in[4];
  const float* b_enc = (const float*)d_in[5];
  const float* W_dec = (const float*)d_in[6];
  const float* W_att = (const float*)d_in[7];
  const float* conv_w = (const float*)d_in[8];
  const float* gvec_w = (const float*)d_in[9];
  // gvec_b shifts all logits equally -> cancels in softmax.

  char* ws = (char*)d_ws;
  u16* encbf = (u16*)ws;    ws += (size_t)MM * EE * 2;     // 128 MB
  u16* Wt = (u16*)ws;       ws += (size_t)EE * DD * 2;     // 2 MB
  u16* attc32 = (u16*)ws;   ws += (size_t)MM * 32 * 2;     // 4 MB
  u16* wattT = (u16*)ws;    ws += (size_t)DD * 32 * 2;     // 64 KB
  float* decp = (float*)ws; ws += (size_t)BB * DD * 4;
  float* ep = (float*)ws;   ws += (size_t)4 * MM * 4;      // 4 partial slabs

  float* c = (float*)d_out;            // [32][1024]
  float* wout = c + BB * DD;           // [32][2048]

  hipFuncSetAttribute((const void*)k_gemm8,
                      hipFuncAttributeMaxDynamicSharedMemorySize, 131072);

  k_prep<<<5264, 256, 0, stream>>>(enc, encbf, W_enc, Wt, att_prev, conv_w,
                                   attc32, dec_z, W_dec, decp, W_att, wattT, c);
  k_gemm8<<<1024, 512, 131072, stream>>>(encbf, Wt, attc32, wattT, b_enc, decp,
                                         gvec_w, ep);
  k_softmax<<<BB, 256, 0, stream>>>(ep, elen, wout);
  k_ctx<<<512, 256, 0, stream>>>(encbf, wout, c);
}

// Round 4
// 609.117 us; speedup vs baseline: 1.2025x; 1.0162x over previous
//
#include <hip/hip_runtime.h>
#include <hip/hip_bf16.h>
#include <math.h>

// Problem constants
#define BB 32
#define TT 2048
#define EE 1024
#define DD 1024
#define MM (BB * TT)   // 65536 rows
#define CC 10
#define FW 201

typedef __attribute__((ext_vector_type(8))) short short8;
typedef __attribute__((ext_vector_type(4))) float f32x4;
typedef __attribute__((ext_vector_type(4))) float f4;
typedef __attribute__((ext_vector_type(8))) unsigned short u16x8;
typedef __attribute__((ext_vector_type(4))) unsigned int u32x4;
typedef unsigned short u16;
typedef unsigned int u32;

__device__ __forceinline__ u16 f2bf(float f) {
  __hip_bfloat16 h = __float2bfloat16(f);
  return *reinterpret_cast<u16*>(&h);
}
__device__ __forceinline__ float bf2f(u16 u) {
  __hip_bfloat16 h;
  *reinterpret_cast<u16*>(&h) = u;
  return __bfloat162float(h);
}
__device__ __forceinline__ u32 cvt_pk_bf16(float lo, float hi) {
  u32 r;
  asm("v_cvt_pk_bf16_f32 %0, %1, %2" : "=v"(r) : "v"(lo), "v"(hi));
  return r;
}
__device__ __forceinline__ float tanh_fast(float x) {
  float ex = __expf(2.f * x);
  return 1.f - 2.f * __builtin_amdgcn_rcpf(ex + 1.f);
}
__device__ __forceinline__ void glds(const u16* src, u16* dst) {
  __builtin_amdgcn_global_load_lds(
      (const __attribute__((address_space(1))) void*)src,
      (__attribute__((address_space(3))) void*)dst, 16, 0, 0);
}

// ---------------- K_prep: cvt | tw | conv | decp | zero-c | wattT ----------
// block ranges: [0,4096) cvt, [4096,4352) tw, [4352,4608) conv,
//               [4608,5120) decp, [5120,5248) zero-c, [5248,5264) wattT
// LDS unioned (max 16.6KB) so the BW-bound cvt blocks get ~9 blocks/CU.
__global__ __launch_bounds__(256) void k_prep(
    const float* __restrict__ enc, u16* __restrict__ encbf,
    const float* __restrict__ W_enc, u16* __restrict__ Wt,
    const float* __restrict__ att_prev, const float* __restrict__ conv_w,
    u16* __restrict__ attc32,
    const float* __restrict__ dec_z, const float* __restrict__ W_dec,
    float* __restrict__ decp,
    const float* __restrict__ W_att, u16* __restrict__ wattT,
    float* __restrict__ c) {
  int bid = blockIdx.x, tid = threadIdx.x;
  __shared__ __align__(16) char shbuf[16704];

  if (bid < 4096) {
    // ---- enc f32 -> bf16, packed cvt, grid-stride (8M u16x8 chunks) ----
    const f4* ep = (const f4*)enc;
    u32x4* op = (u32x4*)encbf;
    for (long i = (long)bid * 256 + tid; i < (long)MM * EE / 8; i += 4096 * 256) {
      f4 x = ep[2 * i], y = ep[2 * i + 1];
      u32x4 o;
      o[0] = cvt_pk_bf16(x[0], x[1]);
      o[1] = cvt_pk_bf16(x[2], x[3]);
      o[2] = cvt_pk_bf16(y[0], y[1]);
      o[3] = cvt_pk_bf16(y[2], y[3]);
      op[i] = o;
    }
  } else if (bid < 4352) {
    // ---- W_enc[k][n] -> Wt bf16 [n][k] ----
    float(*tile)[65] = (float(*)[65])shbuf;     // 64*65*4 = 16640
    int rel = bid - 4096;
    int k0 = (rel & 15) * 64, n0 = (rel >> 4) * 64;
    for (int i = tid; i < 4096; i += 256) {
      int r = i >> 6, cc = i & 63;
      tile[r][cc] = W_enc[(k0 + r) * 1024 + n0 + cc];
    }
    __syncthreads();
    for (int i = tid; i < 4096; i += 256) {
      int nr = i >> 6, kc = i & 63;
      Wt[(n0 + nr) * 1024 + k0 + kc] = f2bf(tile[kc][nr]);
    }
  } else if (bid < 4608) {
    // ---- location conv -> attc32 bf16 [M][32] (cols 10..31 = 0) ----
    float* cw = (float*)shbuf;                  // 2010*4 = 8040
    float* ap = (float*)(shbuf + 8064);         // 456*4 = 1824
    int rel = bid - 4352;
    int b = rel >> 3, t0 = (rel & 7) * 256;
    for (int i = tid; i < CC * FW; i += 256) cw[i] = conv_w[i];
    for (int i = tid; i < 456; i += 256) {
      int t = t0 - 100 + i;
      ap[i] = (t >= 0 && t < TT) ? att_prev[b * TT + t] : 0.f;
    }
    __syncthreads();
    float acc[CC];
#pragma unroll
    for (int cc = 0; cc < CC; ++cc) acc[cc] = 0.f;
    for (int f = 0; f < FW; ++f) {
      float x = ap[tid + f];
#pragma unroll
      for (int cc = 0; cc < CC; ++cc) acc[cc] += x * cw[cc * FW + f];
    }
    u16 row[32];
#pragma unroll
    for (int cc = 0; cc < CC; ++cc) row[cc] = f2bf(acc[cc]);
#pragma unroll
    for (int cc = CC; cc < 32; ++cc) row[cc] = 0;
    u16x8* o = (u16x8*)(attc32 + ((size_t)(b * TT + t0 + tid) << 5));
#pragma unroll
    for (int q = 0; q < 4; ++q) o[q] = *(u16x8*)&row[q * 8];
  } else if (bid < 5120) {
    // ---- dec_proj = dec_z @ W_dec ----
    float* z = (float*)shbuf;                   // 4096
    float(*red)[64] = (float(*)[64])(shbuf + 4096);  // 1024
    int rel = bid - 4608;
    int b = rel >> 4, c0 = (rel & 15) << 6;
    for (int i = tid; i < 1024; i += 256) z[i] = dec_z[(b << 10) + i];
    __syncthreads();
    int d = c0 + (tid & 63), ks = tid >> 6;
    float a = 0.f;
    const float* Wp = W_dec + (size_t)(ks << 8) * 1024 + d;
    const float* zp = z + (ks << 8);
#pragma unroll 4
    for (int k = 0; k < 256; ++k) a += zp[k] * Wp[(size_t)k * 1024];
    red[ks][tid & 63] = a;
    __syncthreads();
    if (tid < 64)
      decp[(b << 10) + c0 + tid] =
          (red[0][tid] + red[1][tid]) + (red[2][tid] + red[3][tid]);
  } else if (bid < 5248) {
    // ---- zero c ----
    c[(bid - 5120) * 256 + tid] = 0.f;
  } else {
    // ---- W_att[10][1024] -> wattT bf16 [1024][32] (rows k>=10 zero) ----
    int n0 = (bid - 5248) << 6;
    if (tid < 64) {
      int n = n0 + tid;
      u16 row[32];
#pragma unroll
      for (int k = 0; k < CC; ++k) row[k] = f2bf(W_att[k * 1024 + n]);
#pragma unroll
      for (int k = CC; k < 32; ++k) row[k] = 0;
      u16x8* o = (u16x8*)(wattT + ((size_t)n << 5));
#pragma unroll
      for (int q = 0; q < 4; ++q) o[q] = *(u16x8*)&row[q * 8];
    }
  }
}

// ---------------- K2: 256x256 8-phase bf16 GEMM + fused tanh/gvec epilogue ----
// BM=BN=256, BK=64, 16 K-tiles, 8 waves (2m x 4n), 512 threads, 128KB LDS.
// 4 half-K slots per matrix (16KB each), ring-rotated; stage 1 half (2 loads)
// per phase; counted vmcnt (schedule identical to round 3, proven sound).
// NEW: all LDS-read addresses are ONE base VGPR + compile-time immediates
// (g = fkg ^ ((frl>>1)&3) is invariant across mi/ni/slot since mi*8 === 0 mod 4)
// and stage addresses are 2 rolling pointers (+64B per stage) -> VALU/phase
// drops from ~390 cyc to ~<100 (was the co-bottleneck with the 512-cyc MFMA floor).
#define VM8 asm volatile("s_waitcnt vmcnt(8)" ::: "memory")
#define VM2 asm volatile("s_waitcnt vmcnt(2)" ::: "memory")
#define VM0 asm volatile("s_waitcnt vmcnt(0)" ::: "memory")

__global__ __launch_bounds__(512, 2) void k_gemm8(
    const u16* __restrict__ A, const u16* __restrict__ Bt,
    const u16* __restrict__ attc32, const u16* __restrict__ wattT,
    const float* __restrict__ benc, const float* __restrict__ decp,
    const float* __restrict__ gvec, float* __restrict__ epart) {
  extern __shared__ u16 smem[];
  u16* sA = smem;               // 4 slots of 8192 u16 (16KB)
  u16* sB = smem + 32768;

  int tid = threadIdx.x;
  int lane = tid & 63, wid = tid >> 6;
  int frl = lane & 15, fkg = lane >> 4;
  int wm = wid >> 2, wn = wid & 3;

  int orig = (blockIdx.x & 7) * 128 + (blockIdx.x >> 3);
  int bm = orig >> 2, bn = orig & 3;
  int brow = bm << 8;
  int bcol = bn << 8;
  int b = brow >> 11;

  // ---- precomputed LDS read bases (swizzle g is thread-constant) ----
  int gRd = fkg ^ ((frl >> 1) & 3);
  const u16* aBase = sA + (((wm << 7) + frl) << 5) + (gRd << 3);
  const u16* bBase = sB + (((wn << 6) + frl) << 5) + (gRd << 3);

  // ---- precomputed stage pointers (roll +32 elems per stage) ----
  int s0 = tid, s1 = 512 + tid;
  int r0 = s0 >> 2, cs0 = (s0 & 3) ^ ((r0 >> 1) & 3);
  int r1 = s1 >> 2, cs1 = (s1 & 3) ^ ((r1 >> 1) & 3);
  const u16* gA0 = A + (size_t)(brow + r0) * 1024 + (cs0 << 3);
  const u16* gA1 = A + (size_t)(brow + r1) * 1024 + (cs1 << 3);
  const u16* gB0 = Bt + (size_t)(bcol + r0) * 1024 + (cs0 << 3);
  const u16* gB1 = Bt + (size_t)(bcol + r1) * 1024 + (cs1 << 3);
  u16* dA0 = sA + ((tid & ~63) << 3);
  u16* dA1 = sA + ((512 + (tid & ~63)) << 3);
  u16* dB0 = sB + ((tid & ~63) << 3);
  u16* dB1 = sB + ((512 + (tid & ~63)) << 3);

#define STA(SLOT) { glds(gA0, dA0 + (SLOT)*8192); glds(gA1, dA1 + (SLOT)*8192); gA0 += 32; gA1 += 32; }
#define STB(SLOT) { glds(gB0, dB0 + (SLOT)*8192); glds(gB1, dB1 + (SLOT)*8192); gB0 += 32; gB1 += 32; }

  f32x4 acc[8][4];
#pragma unroll
  for (int i = 0; i < 8; ++i)
#pragma unroll
    for (int j = 0; j < 4; ++j) acc[i][j] = (f32x4){0.f, 0.f, 0.f, 0.f};
  short8 afr[4], bfr[4];

#define PH(SLOT, CH, STAGE, WAIT)                                             \
  {                                                                           \
    if ((CH) == 0) {                                                          \
      _Pragma("unroll") for (int ni = 0; ni < 4; ++ni)                        \
          bfr[ni] = *(const short8*)(bBase + (SLOT)*8192 + ni * 512);         \
    }                                                                         \
    _Pragma("unroll") for (int i = 0; i < 4; ++i)                             \
        afr[i] = *(const short8*)(aBase + (SLOT)*8192 + ((CH)*4 + i) * 512);  \
    STAGE;                                                                    \
    WAIT;                                                                     \
    __builtin_amdgcn_s_barrier();                                             \
    __builtin_amdgcn_s_setprio(1);                                            \
    _Pragma("unroll") for (int i = 0; i < 4; ++i)                             \
        _Pragma("unroll") for (int ni = 0; ni < 4; ++ni)                      \
            acc[(CH)*4 + i][ni] = __builtin_amdgcn_mfma_f32_16x16x32_bf16(    \
                afr[i], bfr[ni], acc[(CH)*4 + i][ni], 0, 0, 0);               \
    __builtin_amdgcn_s_setprio(0);                                            \
    __builtin_amdgcn_s_barrier();                                             \
  }

  // Prologue: slots 0,1,2 for both matrices (k-offsets 0,32,64; 12 loads)
  STA(0); STB(0);
  STA(1); STB(1);
  STA(2); STB(2);
  VM8;
  __builtin_amdgcn_s_barrier();

#pragma unroll 1
  for (int I = 0; I < 7; ++I) {
    PH(0, 0, STA(3), ((void)0));
    PH(0, 1, STB(3), VM8);
    PH(1, 0, STA(0), ((void)0));
    PH(1, 1, STB(0), VM8);
    PH(2, 0, STA(1), ((void)0));
    PH(2, 1, STB(1), VM8);
    PH(3, 0, STA(2), ((void)0));
    PH(3, 1, STB(2), VM8);
  }
  // Tail (tiles 14,15): stage attc/wattT into dead slot-0 regions; drain.
  PH(0, 0, STA(3), ((void)0));
  PH(0, 1, STB(3), VM8);
  PH(1, 0, ((void)0), ((void)0));
  PH(1, 1, ((void)0), VM2);
  PH(2, 0,
     { const u16* p0 = attc32 + ((size_t)brow << 5) + r0 * 32 + (cs0 << 3);
       const u16* p1 = attc32 + ((size_t)brow << 5) + r1 * 32 + (cs1 << 3);
       glds(p0, dA0); glds(p1, dA1); },
     ((void)0));
  PH(2, 1,
     { const u16* p0 = wattT + ((size_t)bcol << 5) + r0 * 32 + (cs0 << 3);
       const u16* p1 = wattT + ((size_t)bcol << 5) + r1 * 32 + (cs1 << 3);
       glds(p0, dB0); glds(p1, dB1); },
     VM2);
  PH(3, 0, ((void)0), ((void)0));
  PH(3, 1, ((void)0), VM0);
#undef PH
#undef STA
#undef STB

  // ---- rank-32 location update: acc += attc32_frag x wattT_frag (slot 0) ----
  {
    short8 a2[8], b2[4];
#pragma unroll
    for (int ni = 0; ni < 4; ++ni) b2[ni] = *(const short8*)(bBase + ni * 512);
#pragma unroll
    for (int mi = 0; mi < 8; ++mi) a2[mi] = *(const short8*)(aBase + mi * 512);
#pragma unroll
    for (int mi = 0; mi < 8; ++mi)
#pragma unroll
      for (int ni = 0; ni < 4; ++ni)
        acc[mi][ni] = __builtin_amdgcn_mfma_f32_16x16x32_bf16(a2[mi], b2[ni], acc[mi][ni], 0, 0, 0);
  }

  // ---- light epilogue: e_part = sum_col g*tanh(acc + benc + decp) ----
  float* se_ep = (float*)(sB + 3 * 8192);   // dead slot-3 B region
  float colv[4], gv[4];
#pragma unroll
  for (int ni = 0; ni < 4; ++ni) {
    int cl = bcol + (wn << 6) + (ni << 4) + frl;
    colv[ni] = benc[cl] + decp[(b << 10) + cl];
    gv[ni] = gvec[cl];
  }
#pragma unroll
  for (int mi = 0; mi < 8; ++mi) {
#pragma unroll
    for (int j = 0; j < 4; ++j) {
      int rl = (wm << 7) + (mi << 4) + (fkg << 2) + j;
      float esum = 0.f;
#pragma unroll
      for (int ni = 0; ni < 4; ++ni)
        esum += gv[ni] * tanh_fast(acc[mi][ni][j] + colv[ni]);
#pragma unroll
      for (int o = 8; o >= 1; o >>= 1) esum += __shfl_xor(esum, o, 16);
      if (frl == 0) se_ep[(rl << 2) + wn] = esum;
    }
  }
  __syncthreads();
  if (tid < 256)
    epart[bn * MM + brow + tid] =
        (se_ep[(tid << 2) + 0] + se_ep[(tid << 2) + 1]) +
        (se_ep[(tid << 2) + 2] + se_ep[(tid << 2) + 3]);
}

// ---------------- K3: masked softmax(2*e) over 4 partial slabs ----------------
__global__ __launch_bounds__(256) void k_softmax(const float* __restrict__ ep,
                                                 const int* __restrict__ len,
                                                 float* __restrict__ wout) {
  int b = blockIdx.x;
  int L = len[b];
  __shared__ float se[TT];
  __shared__ float red[4], red2[4];
  int tid = threadIdx.x, w = tid >> 6, lane = tid & 63;
  for (int t = tid; t < TT; t += 256) {
    int m = b * TT + t;
    se[t] = (ep[m] + ep[MM + m]) + (ep[2 * MM + m] + ep[3 * MM + m]);
  }
  __syncthreads();
  float mx = -3.4e38f;
  for (int t = tid; t < TT; t += 256)
    if (t < L) mx = fmaxf(mx, se[t]);
  for (int o = 32; o >= 1; o >>= 1) mx = fmaxf(mx, __shfl_xor(mx, o, 64));
  if (lane == 0) red[w] = mx;
  __syncthreads();
  mx = fmaxf(fmaxf(red[0], red[1]), fmaxf(red[2], red[3]));
  float s = 0.f;
  for (int t = tid; t < TT; t += 256)
    if (t < L) s += __expf(2.f * (se[t] - mx));
  for (int o = 32; o >= 1; o >>= 1) s += __shfl_xor(s, o, 64);
  if (lane == 0) red2[w] = s;
  __syncthreads();
  s = (red2[0] + red2[1]) + (red2[2] + red2[3]);
  float inv = 1.f / s;
  for (int t = tid; t < TT; t += 256)
    wout[b * TT + t] = (t < L) ? __expf(2.f * (se[t] - mx)) * inv : 0.f;
}

// ---------------- K4: c[b][d] = sum_t w[b][t] * enc[b][t][d] (short8) --------
__global__ __launch_bounds__(256) void k_ctx(const u16* __restrict__ encbf,
                                             const float* __restrict__ wout,
                                             float* __restrict__ c) {
  int b = blockIdx.x >> 4;
  int t0 = (blockIdx.x & 15) << 7;   // 16 chunks of 128 rows
  int col8 = (threadIdx.x & 127) << 3;
  int rp = threadIdx.x >> 7;
  const float* wb = wout + b * TT + t0;
  float acc[8] = {0, 0, 0, 0, 0, 0, 0, 0};
  for (int tt = rp; tt < 128; tt += 2) {
    float wv = wb[tt];
    if (wv == 0.f) continue;     // wave-uniform skip of masked tail
    u16x8 v = *(const u16x8*)(encbf + (((size_t)(b * TT + t0 + tt)) << 10) + col8);
#pragma unroll
    for (int j = 0; j < 8; ++j) acc[j] += wv * bf2f(v[j]);
  }
  __shared__ float red[128][8];
  if (rp) {
#pragma unroll
    for (int j = 0; j < 8; ++j) red[threadIdx.x & 127][j] = acc[j];
  }
  __syncthreads();
  if (!rp) {
#pragma unroll
    for (int j = 0; j < 8; ++j) acc[j] += red[threadIdx.x][j];
#pragma unroll
    for (int j = 0; j < 8; ++j) atomicAdd(&c[(b << 10) + col8 + j], acc[j]);
  }
}

extern "C" void kernel_launch(void* const* d_in, const int* in_sizes, int n_in,
                              void* d_out, int out_size, void* d_ws, size_t ws_size,
                              hipStream_t stream) {
  const float* enc = (const float*)d_in[0];
  const int* elen = (const int*)d_in[1];
  const float* dec_z = (const float*)d_in[2];
  const float* att_prev = (const float*)d_in[3];
  const float* W_enc = (const float*)d_in[4];
  const float* b_enc = (const float*)d_in[5];
  const float* W_dec = (const float*)d_in[6];
  const float* W_att = (const float*)d_in[7];
  const float* conv_w = (const float*)d_in[8];
  const float* gvec_w = (const float*)d_in[9];
  // gvec_b shifts all logits equally -> cancels in softmax.

  char* ws = (char*)d_ws;
  u16* encbf = (u16*)ws;    ws += (size_t)MM * EE * 2;     // 128 MB
  u16* Wt = (u16*)ws;       ws += (size_t)EE * DD * 2;     // 2 MB
  u16* attc32 = (u16*)ws;   ws += (size_t)MM * 32 * 2;     // 4 MB
  u16* wattT = (u16*)ws;    ws += (size_t)DD * 32 * 2;     // 64 KB
  float* decp = (float*)ws; ws += (size_t)BB * DD * 4;
  float* ep = (float*)ws;   ws += (size_t)4 * MM * 4;      // 4 partial slabs

  float* c = (float*)d_out;            // [32][1024]
  float* wout = c + BB * DD;           // [32][2048]

  hipFuncSetAttribute((const void*)k_gemm8,
                      hipFuncAttributeMaxDynamicSharedMemorySize, 131072);

  k_prep<<<5264, 256, 0, stream>>>(enc, encbf, W_enc, Wt, att_prev, conv_w,
                                   attc32, dec_z, W_dec, decp, W_att, wattT, c);
  k_gemm8<<<1024, 512, 131072, stream>>>(encbf, Wt, attc32, wattT, b_enc, decp,
                                         gvec_w, ep);
  k_softmax<<<BB, 256, 0, stream>>>(ep, elen, wout);
  k_ctx<<<512, 256, 0, stream>>>(encbf, wout, c);
}